// Round 12
// baseline (173.569 us; speedup 1.0000x reference)
//
#include <hip/hip_runtime.h>

// Problem constants
#define BB 16
#define TT 64
#define HH 256
#define NSUB 16              // blocks per batch; block owns a 16-COLUMN slice
#define NBLK (BB * NSUB)     // 256 blocks

// d_out layout (floats): hid[B][T][H], out[B][T][2], h_fin[B][H], new_j[B][H][H]
#define OUT_OFF  (BB * TT * HH)            // 262144
#define HFIN_OFF (OUT_OFF + BB * TT * 2)   // 264192
#define NJ_OFF   (HFIN_OFF + BB * HH)      // 268288

// beta * SIGMA_SYN * sqrt(beta) = 0.1 * 0.002 * sqrt(0.1)
#define C_SN    6.324555320336759e-05f
// PERT_SIGMA * sqrt(ALPHA) = 0.1 * 0.5
#define C_NOISE 0.05f

#define SLOTS_PER_B (2 * NSUB * 16)        // 512 u64 per batch per region

typedef unsigned long long u64;
typedef unsigned int u32;

// Two-tier tagged-packet protocol.
//  FAST tier: workgroup-scope RMWs -> execute at the issuing XCD's L2
//    (no sc1 bypass). Valid only if all 16 blocks of a batch share an XCD
//    (heuristic bid%8 round-robin; b = bid&15 puts batch b on XCD b%8).
//  INSURANCE tier: agent-scope RMWs at the device coherence point (proven
//    r4-r11). Owner dual-publishes; pollers fall back after 32 misses and
//    STICK to insurance -> wrong mapping degrades to ~r11 speed, never hangs.
// Lessons: r2 stale relaxed loads; r6 system-scope HBM flood; r8 chaotic
// recurrence (sn exact); r10 barrier-free + load-poll hang; r11 MALL RT is
// the floor of the agent-only topology.
__device__ __forceinline__ void ag_put(u64* p, u64 v) {
    (void)__hip_atomic_exchange(p, v, __ATOMIC_RELAXED, __HIP_MEMORY_SCOPE_AGENT);
}
__device__ __forceinline__ u64 ag_get(u64* p) {
    return __hip_atomic_fetch_add(p, 0ull, __ATOMIC_RELAXED, __HIP_MEMORY_SCOPE_AGENT);
}
__device__ __forceinline__ void wg_put(u64* p, u64 v) {
    (void)__hip_atomic_exchange(p, v, __ATOMIC_RELAXED, __HIP_MEMORY_SCOPE_WORKGROUP);
}
__device__ __forceinline__ u64 wg_get(u64* p) {
    return __hip_atomic_fetch_add(p, 0ull, __ATOMIC_RELAXED, __HIP_MEMORY_SCOPE_WORKGROUP);
}
__device__ __forceinline__ u64 pack(u32 tag, float v) {
    return ((u64)tag << 32) | (u64)__float_as_uint(v);
}

__global__ __launch_bounds__(256) void rnn_all(
    const float* __restrict__ x,      // [B,T,2]
    const float* __restrict__ h0,     // [B,H]
    const float* __restrict__ w_in,   // [H,2]
    const float* __restrict__ w_hh,   // [H,H]
    const float* __restrict__ b_hh,   // [H]
    const float* __restrict__ w_out,  // [2,H]
    const float* __restrict__ nper,   // [B,H]
    const float* __restrict__ sn,     // [T,B,H,H]
    const int*   __restrict__ pt_ptr, // scalar
    float*       __restrict__ dout,
    u64*         __restrict__ ws)     // d_ws: fast[BB][512] then agent[BB][512]
{
    const int tid = threadIdx.x;
    const int bid = blockIdx.x;
    const int b   = bid & 15;             // batch  (low bits -> one XCD/batch)
    const int sub = bid >> 4;             // column-slice owner
    const int j0  = sub * 16;
    const int q     = tid & 15;           // col within slice
    const int rbase = tid >> 4;           // this thread's rows: i = rbase+16m
    const int jcol  = j0 + q;             // this thread's M column (global)
    const int wv = tid >> 6, ln = tid & 63;

    // s_actT: TRANSPOSED act store: act[i] lives at [(i&15)*16 + (i>>4)]
    // -> thread (rbase,*) reads its 16 operands {rbase+16m} as 4 float4s.
    __shared__ float s_actT[2][HH];
    __shared__ float s_h[2][HH];          // raw h (for out / h_fin shadows)
    __shared__ float s_red[4][16];
    __shared__ float s_o[4][2];
    __shared__ float s_x[2 * TT];
    __shared__ float s_wt[16][HH];        // w_hh rows j0..j0+15

    u64* fastb = ws + (size_t)b * SLOTS_PER_B;
    u64* agb   = ws + (size_t)(BB + b) * SLOTS_PER_B;
    const int pt = *pt_ptr;

    // ---- prologue
    for (int idx = tid; idx < 16 * HH; idx += 256)
        s_wt[idx >> 8][idx & 255] = w_hh[(size_t)(j0 + (idx >> 8)) * HH + (idx & 255)];
    {
        const float hv = h0[b * HH + tid];
        s_h[0][tid] = hv;
        s_actT[0][(tid & 15) * 16 + (tid >> 4)] = tanhf(hv);
    }
    if (tid < 2 * TT) s_x[tid] = x[b * 2 * TT + tid];

    float wi0 = 0.f, wi1 = 0.f, bh = 0.f, npv = 0.f, hreg = 0.f;
    if (tid < 16) {
        wi0  = w_in[jcol * 2 + 0];
        wi1  = w_in[jcol * 2 + 1];
        bh   = b_hh[jcol];
        npv  = nper[b * HH + jcol] * C_NOISE;
        hreg = h0[b * HH + jcol];
    }
    const float wo0 = w_out[tid], wo1 = w_out[HH + tid];
    __syncthreads();

    // M[m] = M[i][jcol], i = rbase+16m ; init = w_hh[jcol][i] (diff = 0)
    float M[16];
    #pragma unroll
    for (int m = 0; m < 16; ++m) M[m] = s_wt[q][rbase + 16 * m];

    // sn prefetch t=0: sn[0][b][i][jcol]
    float sreg[16];
    {
        const float* snp = sn + ((size_t)b * HH + rbase) * HH + jcol;
        #pragma unroll
        for (int m = 0; m < 16; ++m) sreg[m] = snp[(size_t)(16 * m) * HH];
    }

    bool useins = false;                  // sticky insurance-tier flag

    for (int t = 0; t < TT; ++t) {
        const int cur = t & 1, nxt = cur ^ 1;
        const u32 tagw = (u32)(t + 1);

        // ---- dot: act operands contiguous in s_actT -> 4 ds_read_b128
        float a[16];
        #pragma unroll
        for (int mq = 0; mq < 4; ++mq) {
            float4 v = *(const float4*)&s_actT[cur][rbase * 16 + mq * 4];
            a[mq * 4 + 0] = v.x; a[mq * 4 + 1] = v.y;
            a[mq * 4 + 2] = v.z; a[mq * 4 + 3] = v.w;
        }
        float p = 0.f;
        #pragma unroll
        for (int m = 0; m < 16; ++m) p += a[m] * M[m];
        p += __shfl_xor(p, 16, 64);       // combine rbase ^1
        p += __shfl_xor(p, 32, 64);       // combine rbase ^2
        if (ln < 16) s_red[wv][ln] = p;   // 4 wave-partials per column
        __syncthreads();                  // SYNC1

        // ---- owner: h update for own 16 columns, DUAL publish immediately
        if (tid < 16) {
            const float dj = s_red[0][tid] + s_red[1][tid]
                           + s_red[2][tid] + s_red[3][tid];
            const float tmp = s_x[2 * t] * wi0 + s_x[2 * t + 1] * wi1 + bh + dj;
            hreg = 0.75f * hreg + 0.25f * tmp + ((t == pt) ? npv : 0.f);
            const u64 pk = pack(tagw, hreg);
            const int sidx = (cur * NSUB + sub) * 16 + tid;
            wg_put(fastb + sidx, pk);      // XCD-L2 fast tier
            ag_put(agb + sidx, pk);        // MALL insurance tier
            s_h[nxt][jcol] = hreg;
            s_actT[nxt][q * 16 + sub] = tanhf(hreg);
            dout[((size_t)b * TT + t) * HH + jcol] = hreg;   // hid
        }

        // ---- shadow: M step-t update (outer + sn[t]), prefetch sn[t+1]
        const float aj = s_actT[cur][q * 16 + sub];          // act[jcol]
        #pragma unroll
        for (int m = 0; m < 16; ++m)
            M[m] += C_SN * sreg[m] - 0.1f * a[m] * aj;
        if (t + 1 < TT) {
            const float* snp = sn + (((size_t)(t + 1) * BB + b) * HH + rbase) * HH + jcol;
            #pragma unroll
            for (int m = 0; m < 16; ++m) sreg[m] = snp[(size_t)(16 * m) * HH];
        }
        // sub1 shadow: out[b][t-1] = h_t @ w_out^T  (h_t = s_h[cur], stable)
        if (sub == 1) {
            const float hv = s_h[cur][tid];
            float p0 = hv * wo0, p1 = hv * wo1;
            #pragma unroll
            for (int off = 32; off; off >>= 1) {
                p0 += __shfl_down(p0, off, 64);
                p1 += __shfl_down(p1, off, 64);
            }
            if (ln == 0) { s_o[wv][0] = p0; s_o[wv][1] = p1; }
        }

        // ---- poll: ONE foreign slot per thread. Fast tier (XCD-L2 RMW)
        // first; after 32 misses stick to the insurance tier forever.
        if (tid < 240) {
            int fs = tid >> 4; fs += (fs >= sub);            // foreign sub id
            const int fq = tid & 15;
            const int sidx = (cur * NSUB + fs) * 16 + fq;
            u64 v;
            if (!useins) {
                u64* fp = fastb + sidx;
                v = wg_get(fp);
                int tries = 0;
                while ((u32)(v >> 32) != tagw && ++tries < 32) v = wg_get(fp);
                if ((u32)(v >> 32) != tagw) useins = true;
            }
            if (useins) {
                u64* ap = agb + sidx;
                v = ag_get(ap);
                while ((u32)(v >> 32) != tagw) {
                    __builtin_amdgcn_s_sleep(1);
                    v = ag_get(ap);
                }
            }
            const float hr = __uint_as_float((u32)v);
            s_h[nxt][fs * 16 + fq] = hr;
            s_actT[nxt][fq * 16 + fs] = tanhf(hr);           // fused tanh
        }
        __syncthreads();                  // SYNC2: s_h/s_actT[nxt] complete

        if (sub == 1 && tid == 0 && t > 0) {
            dout[OUT_OFF + ((size_t)b * TT + (t - 1)) * 2 + 0] =
                s_o[0][0] + s_o[1][0] + s_o[2][0] + s_o[3][0];
            dout[OUT_OFF + ((size_t)b * TT + (t - 1)) * 2 + 1] =
                s_o[0][1] + s_o[1][1] + s_o[2][1] + s_o[3][1];
        }
    }

    // ---- epilogue: s_h[0] = h_64 (TT even)
    if (sub == 1) {
        const float hv = s_h[0][tid];
        float p0 = hv * wo0, p1 = hv * wo1;
        #pragma unroll
        for (int off = 32; off; off >>= 1) {
            p0 += __shfl_down(p0, off, 64);
            p1 += __shfl_down(p1, off, 64);
        }
        if (ln == 0) { s_o[wv][0] = p0; s_o[wv][1] = p1; }
        __syncthreads();                   // block-uniform branch: legal
        if (tid == 0) {
            dout[OUT_OFF + ((size_t)b * TT + (TT - 1)) * 2 + 0] =
                s_o[0][0] + s_o[1][0] + s_o[2][0] + s_o[3][0];
            dout[OUT_OFF + ((size_t)b * TT + (TT - 1)) * 2 + 1] =
                s_o[0][1] + s_o[1][1] + s_o[2][1] + s_o[3][1];
        }
    }
    if (sub == 2) dout[HFIN_OFF + b * HH + tid] = s_h[0][tid];

    // new_j[b][i][jcol] = w_hh[i][jcol] + (M - w_hh[jcol][i])
    #pragma unroll
    for (int m = 0; m < 16; ++m) {
        const int i = rbase + 16 * m;
        dout[NJ_OFF + ((size_t)b * HH + i) * HH + jcol] =
            w_hh[(size_t)i * HH + jcol] + M[m] - s_wt[q][i];
    }
}

extern "C" void kernel_launch(void* const* d_in, const int* in_sizes, int n_in,
                              void* d_out, int out_size, void* d_ws, size_t ws_size,
                              hipStream_t stream) {
    (void)in_sizes; (void)n_in; (void)out_size; (void)ws_size;
    const float* x     = (const float*)d_in[0];
    const float* h0    = (const float*)d_in[1];
    const float* w_in  = (const float*)d_in[2];
    const float* w_hh  = (const float*)d_in[3];
    const float* b_hh  = (const float*)d_in[4];
    const float* w_out = (const float*)d_in[5];
    const float* nper  = (const float*)d_in[6];
    const float* sn    = (const float*)d_in[7];
    const int*   pt    = (const int*)d_in[8];
    float* dout        = (float*)d_out;
    u64* ws            = (u64*)d_ws;

    // zero BOTH slot tiers each launch: tags in [1,64]; a replayed graph
    // must not see the previous launch's tags as valid.
    hipMemsetAsync(d_ws, 0, (size_t)2 * BB * SLOTS_PER_B * sizeof(u64), stream);

    rnn_all<<<dim3(NBLK), dim3(256), 0, stream>>>(
        x, h0, w_in, w_hh, b_hh, w_out, nper, sn, pt, dout, ws);
}

// Round 13
// 162.933 us; speedup vs baseline: 1.0653x; 1.0653x over previous
//
#include <hip/hip_runtime.h>

// Problem constants
#define BB 16
#define TT 64
#define HH 256
#define NSUB 16              // blocks per batch; block owns a 16-COLUMN slice
#define NBLK (BB * NSUB)     // 256 blocks

// d_out layout (floats): hid[B][T][H], out[B][T][2], h_fin[B][H], new_j[B][H][H]
#define OUT_OFF  (BB * TT * HH)            // 262144
#define HFIN_OFF (OUT_OFF + BB * TT * 2)   // 264192
#define NJ_OFF   (HFIN_OFF + BB * HH)      // 268288

// beta * SIGMA_SYN * sqrt(beta) = 0.1 * 0.002 * sqrt(0.1)
#define C_SN    6.324555320336759e-05f
// PERT_SIGMA * sqrt(ALPHA) = 0.1 * 0.5
#define C_NOISE 0.05f

#define SLOTS_PER_B (2 * NSUB * 16)        // 512 u64 per batch per region

typedef unsigned long long u64;
typedef unsigned int u32;

// ---------------- Two-tier tagged-packet protocol ----------------
// FAST tier: inline-asm global_atomic_*_x2 with sc0 only (NO sc1) ->
//   executes at the issuing XCD's shared L2. Valid because r12's FETCH
//   halving PROVED the b=bid&15 mapping co-locates a batch's 16 blocks on
//   one XCD (bid%8 round-robin). HIP 'workgroup' scope did NOT provide
//   this (r12: never observed the publish); the ISA flag does.
// INSURANCE tier: agent-scope RMWs at the MALL (proven r4-r11). Owner
//   dual-publishes; pollers stick to insurance after 48 fast misses ->
//   wrong mapping degrades to ~r12 speed, never hangs, never corrupts.
// Lessons: r2 stale relaxed loads; r6 system-scope HBM flood; r8 chaotic
// recurrence (sn exact); r10 load-poll hang; r11 MALL RT ~2us/step floor.
__device__ __forceinline__ void ag_put(u64* p, u64 v) {
    (void)__hip_atomic_exchange(p, v, __ATOMIC_RELAXED, __HIP_MEMORY_SCOPE_AGENT);
}
__device__ __forceinline__ u64 ag_get(u64* p) {
    return __hip_atomic_fetch_add(p, 0ull, __ATOMIC_RELAXED, __HIP_MEMORY_SCOPE_AGENT);
}
// XCD-L2 atomic exchange (publish). sc0 = return old (required for atomicity
// with return); no sc1 -> executes at local XCD L2.
__device__ __forceinline__ void l2_put(u64* p, u64 v) {
    u64 old;
    asm volatile("global_atomic_swap_x2 %0, %1, %2, off sc0\n\t"
                 "s_waitcnt vmcnt(0)"
                 : "=v"(old) : "v"(p), "v"(v) : "memory");
    (void)old;
}
// XCD-L2 atomic read (poll): add 0, returns current value, cannot be stale
// within the XCD (executes at the shared L2).
__device__ __forceinline__ u64 l2_get(u64* p) {
    u64 old;
    asm volatile("global_atomic_add_x2 %0, %1, %2, off sc0\n\t"
                 "s_waitcnt vmcnt(0)"
                 : "=v"(old) : "v"(p), "v"(0ull) : "memory");
    return old;
}
__device__ __forceinline__ u64 pack(u32 tag, float v) {
    return ((u64)tag << 32) | (u64)__float_as_uint(v);
}

__global__ __launch_bounds__(256) void rnn_all(
    const float* __restrict__ x,      // [B,T,2]
    const float* __restrict__ h0,     // [B,H]
    const float* __restrict__ w_in,   // [H,2]
    const float* __restrict__ w_hh,   // [H,H]
    const float* __restrict__ b_hh,   // [H]
    const float* __restrict__ w_out,  // [2,H]
    const float* __restrict__ nper,   // [B,H]
    const float* __restrict__ sn,     // [T,B,H,H]
    const int*   __restrict__ pt_ptr, // scalar
    float*       __restrict__ dout,
    u64*         __restrict__ ws)     // d_ws: fast[BB][512] then agent[BB][512]
{
    const int tid = threadIdx.x;
    const int bid = blockIdx.x;
    const int b   = bid & 15;             // batch (low bits -> one XCD/batch)
    const int sub = bid >> 4;             // column-slice owner
    const int j0  = sub * 16;
    const int q     = tid & 15;           // col within slice
    const int rbase = tid >> 4;           // this thread's rows: i = rbase+16m
    const int jcol  = j0 + q;             // this thread's M column (global)
    const int wv = tid >> 6, ln = tid & 63;

    // s_actT: TRANSPOSED act store: act[i] lives at [(i&15)*16 + (i>>4)]
    // -> thread (rbase,*) reads its 16 operands {rbase+16m} as 4 float4s.
    __shared__ float s_actT[2][HH];
    __shared__ float s_h[2][HH];          // raw h (for out / h_fin shadows)
    __shared__ float s_red[4][16];
    __shared__ float s_o[4][2];
    __shared__ float s_x[2 * TT];
    __shared__ float s_wt[16][HH];        // w_hh rows j0..j0+15

    u64* fastb = ws + (size_t)b * SLOTS_PER_B;
    u64* agb   = ws + (size_t)(BB + b) * SLOTS_PER_B;
    const int pt = *pt_ptr;

    // ---- prologue
    for (int idx = tid; idx < 16 * HH; idx += 256)
        s_wt[idx >> 8][idx & 255] = w_hh[(size_t)(j0 + (idx >> 8)) * HH + (idx & 255)];
    {
        const float hv = h0[b * HH + tid];
        s_h[0][tid] = hv;
        s_actT[0][(tid & 15) * 16 + (tid >> 4)] = tanhf(hv);
    }
    if (tid < 2 * TT) s_x[tid] = x[b * 2 * TT + tid];

    float wi0 = 0.f, wi1 = 0.f, bh = 0.f, npv = 0.f, hreg = 0.f;
    if (tid < 16) {
        wi0  = w_in[jcol * 2 + 0];
        wi1  = w_in[jcol * 2 + 1];
        bh   = b_hh[jcol];
        npv  = nper[b * HH + jcol] * C_NOISE;
        hreg = h0[b * HH + jcol];
    }
    const float wo0 = w_out[tid], wo1 = w_out[HH + tid];
    __syncthreads();

    // M[m] = M[i][jcol], i = rbase+16m ; init = w_hh[jcol][i] (diff = 0)
    float M[16];
    #pragma unroll
    for (int m = 0; m < 16; ++m) M[m] = s_wt[q][rbase + 16 * m];

    // sn prefetch t=0: sn[0][b][i][jcol]
    float sreg[16];
    {
        const float* snp = sn + ((size_t)b * HH + rbase) * HH + jcol;
        #pragma unroll
        for (int m = 0; m < 16; ++m) sreg[m] = snp[(size_t)(16 * m) * HH];
    }

    bool useins = false;                  // sticky insurance-tier flag

    for (int t = 0; t < TT; ++t) {
        const int cur = t & 1, nxt = cur ^ 1;
        const u32 tagw = (u32)(t + 1);

        // ---- dot: act operands contiguous in s_actT -> 4 ds_read_b128
        float a[16];
        #pragma unroll
        for (int mq = 0; mq < 4; ++mq) {
            float4 v = *(const float4*)&s_actT[cur][rbase * 16 + mq * 4];
            a[mq * 4 + 0] = v.x; a[mq * 4 + 1] = v.y;
            a[mq * 4 + 2] = v.z; a[mq * 4 + 3] = v.w;
        }
        float p = 0.f;
        #pragma unroll
        for (int m = 0; m < 16; ++m) p += a[m] * M[m];
        p += __shfl_xor(p, 16, 64);       // combine rbase ^1
        p += __shfl_xor(p, 32, 64);       // combine rbase ^2
        if (ln < 16) s_red[wv][ln] = p;   // 4 wave-partials per column
        __syncthreads();                  // SYNC1

        // ---- owner: h update for own 16 columns, DUAL publish immediately
        if (tid < 16) {
            const float dj = s_red[0][tid] + s_red[1][tid]
                           + s_red[2][tid] + s_red[3][tid];
            const float tmp = s_x[2 * t] * wi0 + s_x[2 * t + 1] * wi1 + bh + dj;
            hreg = 0.75f * hreg + 0.25f * tmp + ((t == pt) ? npv : 0.f);
            const u64 pk = pack(tagw, hreg);
            const int sidx = (cur * NSUB + sub) * 16 + tid;
            l2_put(fastb + sidx, pk);      // XCD-L2 fast tier (latency-critical)
            s_h[nxt][jcol] = hreg;
            s_actT[nxt][q * 16 + sub] = tanhf(hreg);
            dout[((size_t)b * TT + t) * HH + jcol] = hreg;   // hid
            ag_put(agb + sidx, pk);        // MALL insurance tier
        }

        // ---- shadow: M step-t update (outer + sn[t]), prefetch sn[t+1]
        const float aj = s_actT[cur][q * 16 + sub];          // act[jcol]
        #pragma unroll
        for (int m = 0; m < 16; ++m)
            M[m] += C_SN * sreg[m] - 0.1f * a[m] * aj;
        if (t + 1 < TT) {
            const float* snp = sn + (((size_t)(t + 1) * BB + b) * HH + rbase) * HH + jcol;
            #pragma unroll
            for (int m = 0; m < 16; ++m) sreg[m] = snp[(size_t)(16 * m) * HH];
        }
        // sub1 shadow: out[b][t-1] = h_t @ w_out^T  (h_t = s_h[cur], stable)
        if (sub == 1) {
            const float hv = s_h[cur][tid];
            float p0 = hv * wo0, p1 = hv * wo1;
            #pragma unroll
            for (int off = 32; off; off >>= 1) {
                p0 += __shfl_down(p0, off, 64);
                p1 += __shfl_down(p1, off, 64);
            }
            if (ln == 0) { s_o[wv][0] = p0; s_o[wv][1] = p1; }
        }

        // ---- poll: ONE foreign slot per thread. XCD-L2 RMW first (48
        // throttled tries); on exhaustion stick to the MALL insurance tier.
        if (tid < 240) {
            int fs = tid >> 4; fs += (fs >= sub);            // foreign sub id
            const int fq = tid & 15;
            const int sidx = (cur * NSUB + fs) * 16 + fq;
            u64 v = 0;
            if (!useins) {
                u64* fp = fastb + sidx;
                v = l2_get(fp);
                int tries = 0;
                while ((u32)(v >> 32) != tagw && ++tries < 48) {
                    __builtin_amdgcn_s_sleep(1);
                    v = l2_get(fp);
                }
                if ((u32)(v >> 32) != tagw) useins = true;
            }
            if (useins) {
                u64* ap = agb + sidx;
                v = ag_get(ap);
                while ((u32)(v >> 32) != tagw) {
                    __builtin_amdgcn_s_sleep(1);
                    v = ag_get(ap);
                }
            }
            const float hr = __uint_as_float((u32)v);
            s_h[nxt][fs * 16 + fq] = hr;
            s_actT[nxt][fq * 16 + fs] = tanhf(hr);           // fused tanh
        }
        __syncthreads();                  // SYNC2: s_h/s_actT[nxt] complete

        if (sub == 1 && tid == 0 && t > 0) {
            dout[OUT_OFF + ((size_t)b * TT + (t - 1)) * 2 + 0] =
                s_o[0][0] + s_o[1][0] + s_o[2][0] + s_o[3][0];
            dout[OUT_OFF + ((size_t)b * TT + (t - 1)) * 2 + 1] =
                s_o[0][1] + s_o[1][1] + s_o[2][1] + s_o[3][1];
        }
    }

    // ---- epilogue: s_h[0] = h_64 (TT even)
    if (sub == 1) {
        const float hv = s_h[0][tid];
        float p0 = hv * wo0, p1 = hv * wo1;
        #pragma unroll
        for (int off = 32; off; off >>= 1) {
            p0 += __shfl_down(p0, off, 64);
            p1 += __shfl_down(p1, off, 64);
        }
        if (ln == 0) { s_o[wv][0] = p0; s_o[wv][1] = p1; }
        __syncthreads();                   // block-uniform branch: legal
        if (tid == 0) {
            dout[OUT_OFF + ((size_t)b * TT + (TT - 1)) * 2 + 0] =
                s_o[0][0] + s_o[1][0] + s_o[2][0] + s_o[3][0];
            dout[OUT_OFF + ((size_t)b * TT + (TT - 1)) * 2 + 1] =
                s_o[0][1] + s_o[1][1] + s_o[2][1] + s_o[3][1];
        }
    }
    if (sub == 2) dout[HFIN_OFF + b * HH + tid] = s_h[0][tid];

    // new_j[b][i][jcol] = w_hh[i][jcol] + (M - w_hh[jcol][i])
    #pragma unroll
    for (int m = 0; m < 16; ++m) {
        const int i = rbase + 16 * m;
        dout[NJ_OFF + ((size_t)b * HH + i) * HH + jcol] =
            w_hh[(size_t)i * HH + jcol] + M[m] - s_wt[q][i];
    }
}

extern "C" void kernel_launch(void* const* d_in, const int* in_sizes, int n_in,
                              void* d_out, int out_size, void* d_ws, size_t ws_size,
                              hipStream_t stream) {
    (void)in_sizes; (void)n_in; (void)out_size; (void)ws_size;
    const float* x     = (const float*)d_in[0];
    const float* h0    = (const float*)d_in[1];
    const float* w_in  = (const float*)d_in[2];
    const float* w_hh  = (const float*)d_in[3];
    const float* b_hh  = (const float*)d_in[4];
    const float* w_out = (const float*)d_in[5];
    const float* nper  = (const float*)d_in[6];
    const float* sn    = (const float*)d_in[7];
    const int*   pt    = (const int*)d_in[8];
    float* dout        = (float*)d_out;
    u64* ws            = (u64*)d_ws;

    // zero BOTH slot tiers each launch: tags in [1,64]; a replayed graph
    // must not see the previous launch's tags as valid.
    hipMemsetAsync(d_ws, 0, (size_t)2 * BB * SLOTS_PER_B * sizeof(u64), stream);

    rnn_all<<<dim3(NBLK), dim3(256), 0, stream>>>(
        x, h0, w_in, w_hh, b_hh, w_out, nper, sn, pt, dout, ws);
}

// Round 14
// 135.790 us; speedup vs baseline: 1.2782x; 1.1999x over previous
//
#include <hip/hip_runtime.h>

// Problem constants
#define BB 16
#define TT 64
#define HH 256
#define NSUB 16              // blocks per batch; block owns a 16-COLUMN slice
#define NBLK (BB * NSUB)     // 256 blocks

// d_out layout (floats): hid[B][T][H], out[B][T][2], h_fin[B][H], new_j[B][H][H]
#define OUT_OFF  (BB * TT * HH)            // 262144
#define HFIN_OFF (OUT_OFF + BB * TT * 2)   // 264192
#define NJ_OFF   (HFIN_OFF + BB * HH)      // 268288

// beta * SIGMA_SYN * sqrt(beta) = 0.1 * 0.002 * sqrt(0.1)
#define C_SN    6.324555320336759e-05f
// PERT_SIGMA * sqrt(ALPHA) = 0.1 * 0.5
#define C_NOISE 0.05f

typedef unsigned long long u64;
typedef unsigned int u32;

// Agent-scope RMWs ONLY (proven r4-r13): execute at the device coherence
// point; exchange publishes, fetch_add(0) reads fresh; tag travels with the
// data. Lessons: r2 stale relaxed loads; r6 system-scope HBM flood; r8
// chaotic recurrence (sn exact); r10 load-poll hang; r12/r13 XCD-local
// tiers don't engage/pay. NEW (r14): __syncthreads drains vmcnt(0) before
// s_barrier, so the sn prefetch was NEVER in the poll shadow -> LDS-only
// barriers + prefetch-at-top + deferred fold keep it in flight.
__device__ __forceinline__ void slot_put(u64* p, u64 v) {
    (void)__hip_atomic_exchange(p, v, __ATOMIC_RELAXED, __HIP_MEMORY_SCOPE_AGENT);
}
__device__ __forceinline__ u64 slot_get(u64* p) {
    return __hip_atomic_fetch_add(p, 0ull, __ATOMIC_RELAXED, __HIP_MEMORY_SCOPE_AGENT);
}
__device__ __forceinline__ u64 pack(u32 tag, float v) {
    return ((u64)tag << 32) | (u64)__float_as_uint(v);
}

// LDS-only barrier: drains DS ops (lgkmcnt) but NOT vmem (vmcnt), so sn
// prefetch loads + the publish atomic stay in flight across it. Producer
// pattern per ISA: waitcnt THEN s_barrier. sched_barrier(0) fences keep the
// backend from sliding ds ops into/past the sequence (rule #18).
#define LGKM_BAR() do {                                          \
    asm volatile("s_waitcnt lgkmcnt(0)" ::: "memory");           \
    __builtin_amdgcn_sched_barrier(0);                           \
    __builtin_amdgcn_s_barrier();                                \
    __builtin_amdgcn_sched_barrier(0);                           \
} while (0)

// One time-step. CUR/NXT are compile-time 0/1; BF = buffer holding sn[T-1]
// (folded here, loads issued one full step ago = complete); BI = buffer to
// issue sn[T] into (drained at this step's poll, covered by fold+dot+SYNC1).
#define STEP(T, CUR, NXT, BF, BI)                                            \
{                                                                            \
    const u32 tagw = (u32)((T) + 1);                                         \
    if ((T) > 0) {                                                           \
        _Pragma("unroll")                                                    \
        for (int m = 0; m < 16; ++m) M[m] += C_SN * BF[m];                   \
    }                                                                        \
    {                                                                        \
        const float* snp = sn + (((size_t)(T) * BB + b) * HH + rbase) * HH + jcol; \
        _Pragma("unroll")                                                    \
        for (int m = 0; m < 16; ++m) BI[m] = snp[(size_t)(16 * m) * HH];     \
    }                                                                        \
    /* dot: act operands contiguous in s_actT -> 4 ds_read_b128 */           \
    float a[16];                                                             \
    _Pragma("unroll")                                                        \
    for (int mq = 0; mq < 4; ++mq) {                                         \
        float4 v = *(const float4*)&s_actT[CUR][rbase * 16 + mq * 4];        \
        a[mq * 4 + 0] = v.x; a[mq * 4 + 1] = v.y;                            \
        a[mq * 4 + 2] = v.z; a[mq * 4 + 3] = v.w;                            \
    }                                                                        \
    float p = 0.f;                                                           \
    _Pragma("unroll")                                                        \
    for (int m = 0; m < 16; ++m) p += a[m] * M[m];                           \
    p += __shfl_xor(p, 16, 64);                                              \
    p += __shfl_xor(p, 32, 64);                                              \
    if (ln < 16) s_red[wv][ln] = p;                                          \
    LGKM_BAR();                              /* SYNC1: LDS-only */           \
    if (tid < 16) {                                                          \
        const float dj = s_red[0][tid] + s_red[1][tid]                       \
                       + s_red[2][tid] + s_red[3][tid];                      \
        const float tmp = s_x[2 * (T)] * wi0 + s_x[2 * (T) + 1] * wi1        \
                        + bh + dj;                                           \
        hreg = 0.75f * hreg + 0.25f * tmp + (((T) == pt) ? npv : 0.f);       \
        slot_put(slotb + ((CUR) * NSUB + sub) * 16 + tid, pack(tagw, hreg)); \
        s_h[NXT][jcol] = hreg;                                               \
        s_actT[NXT][q * 16 + sub] = tanhf(hreg);                             \
        dout[((size_t)b * TT + (T)) * HH + jcol] = hreg;                     \
    }                                                                        \
    /* shadow: anti-Hebbian fold (register-only) + sub1 out reduce */        \
    {                                                                        \
        const float aj = s_actT[CUR][q * 16 + sub];                          \
        _Pragma("unroll")                                                    \
        for (int m = 0; m < 16; ++m) M[m] -= 0.1f * a[m] * aj;               \
    }                                                                        \
    if (sub == 1) {                                                          \
        const float hv = s_h[CUR][tid];                                      \
        float p0 = hv * wo0, p1 = hv * wo1;                                  \
        _Pragma("unroll")                                                    \
        for (int off = 32; off; off >>= 1) {                                 \
            p0 += __shfl_down(p0, off, 64);                                  \
            p1 += __shfl_down(p1, off, 64);                                  \
        }                                                                    \
        if (ln == 0) { s_o[wv][0] = p0; s_o[wv][1] = p1; }                   \
    }                                                                        \
    /* poll: ONE foreign slot per thread, throttled agent-RMW spin */        \
    if (tid < 240) {                                                         \
        int fs = tid >> 4; fs += (fs >= sub);                                \
        const int fq = tid & 15;                                             \
        u64* sp = slotb + ((CUR) * NSUB + fs) * 16 + fq;                     \
        u64 v = slot_get(sp);                                                \
        while ((u32)(v >> 32) != tagw) {                                     \
            __builtin_amdgcn_s_sleep(1);                                     \
            v = slot_get(sp);                                                \
        }                                                                    \
        const float hr = __uint_as_float((u32)v);                            \
        s_h[NXT][fs * 16 + fq] = hr;                                         \
        s_actT[NXT][fq * 16 + fs] = tanhf(hr);                               \
    }                                                                        \
    LGKM_BAR();                              /* SYNC2: LDS-only */           \
    if (sub == 1 && tid == 0 && (T) > 0) {                                   \
        dout[OUT_OFF + ((size_t)b * TT + ((T) - 1)) * 2 + 0] =               \
            s_o[0][0] + s_o[1][0] + s_o[2][0] + s_o[3][0];                   \
        dout[OUT_OFF + ((size_t)b * TT + ((T) - 1)) * 2 + 1] =               \
            s_o[0][1] + s_o[1][1] + s_o[2][1] + s_o[3][1];                   \
    }                                                                        \
}

__global__ __launch_bounds__(256) void rnn_all(
    const float* __restrict__ x,      // [B,T,2]
    const float* __restrict__ h0,     // [B,H]
    const float* __restrict__ w_in,   // [H,2]
    const float* __restrict__ w_hh,   // [H,H]
    const float* __restrict__ b_hh,   // [H]
    const float* __restrict__ w_out,  // [2,H]
    const float* __restrict__ nper,   // [B,H]
    const float* __restrict__ sn,     // [T,B,H,H]
    const int*   __restrict__ pt_ptr, // scalar
    float*       __restrict__ dout,
    u64*         __restrict__ ws)     // d_ws: [BB][2][NSUB][16] u64 slots
{
    const int tid = threadIdx.x;
    const int bid = blockIdx.x;
    const int b   = bid >> 4;             // batch (r11 mapping, proven fastest)
    const int sub = bid & 15;             // column-slice owner
    const int j0  = sub * 16;
    const int q     = tid & 15;           // col within slice
    const int rbase = tid >> 4;           // this thread's rows: i = rbase+16m
    const int jcol  = j0 + q;             // this thread's M column (global)
    const int wv = tid >> 6, ln = tid & 63;

    // s_actT: act[i] stored TRANSPOSED at [(i&15)*16 + (i>>4)]
    __shared__ float s_actT[2][HH];
    __shared__ float s_h[2][HH];
    __shared__ float s_red[4][16];
    __shared__ float s_o[4][2];
    __shared__ float s_x[2 * TT];
    __shared__ float s_wt[16][HH];        // w_hh rows j0..j0+15

    u64* slotb = ws + (size_t)b * (2 * NSUB * 16);
    const int pt = *pt_ptr;

    // ---- prologue
    for (int idx = tid; idx < 16 * HH; idx += 256)
        s_wt[idx >> 8][idx & 255] = w_hh[(size_t)(j0 + (idx >> 8)) * HH + (idx & 255)];
    {
        const float hv = h0[b * HH + tid];
        s_h[0][tid] = hv;
        s_actT[0][(tid & 15) * 16 + (tid >> 4)] = tanhf(hv);
    }
    if (tid < 2 * TT) s_x[tid] = x[b * 2 * TT + tid];

    float wi0 = 0.f, wi1 = 0.f, bh = 0.f, npv = 0.f, hreg = 0.f;
    if (tid < 16) {
        wi0  = w_in[jcol * 2 + 0];
        wi1  = w_in[jcol * 2 + 1];
        bh   = b_hh[jcol];
        npv  = nper[b * HH + jcol] * C_NOISE;
        hreg = h0[b * HH + jcol];
    }
    const float wo0 = w_out[tid], wo1 = w_out[HH + tid];
    __syncthreads();

    // M[m] = M[i][jcol], i = rbase+16m ; init = w_hh[jcol][i] (diff = 0)
    float M[16];
    #pragma unroll
    for (int m = 0; m < 16; ++m) M[m] = s_wt[q][rbase + 16 * m];

    // Two named sn buffers (static indexing, rule #20): even steps issue
    // into bufA, odd steps into bufB; fold happens one step later.
    float bufA[16], bufB[16];

    for (int tt = 0; tt < TT; tt += 2) {
        STEP(tt,     0, 1, bufB, bufA)
        STEP(tt + 1, 1, 0, bufA, bufB)
    }

    // ---- epilogue: fold sn[63] (odd -> bufB; loads long complete)
    #pragma unroll
    for (int m = 0; m < 16; ++m) M[m] += C_SN * bufB[m];

    // out[b][63] from s_h[0] = hid[63] (step 63: NXT=0)
    if (sub == 1) {
        const float hv = s_h[0][tid];
        float p0 = hv * wo0, p1 = hv * wo1;
        #pragma unroll
        for (int off = 32; off; off >>= 1) {
            p0 += __shfl_down(p0, off, 64);
            p1 += __shfl_down(p1, off, 64);
        }
        if (ln == 0) { s_o[wv][0] = p0; s_o[wv][1] = p1; }
        __syncthreads();                   // block-uniform branch: legal
        if (tid == 0) {
            dout[OUT_OFF + ((size_t)b * TT + (TT - 1)) * 2 + 0] =
                s_o[0][0] + s_o[1][0] + s_o[2][0] + s_o[3][0];
            dout[OUT_OFF + ((size_t)b * TT + (TT - 1)) * 2 + 1] =
                s_o[0][1] + s_o[1][1] + s_o[2][1] + s_o[3][1];
        }
    }
    if (sub == 2) dout[HFIN_OFF + b * HH + tid] = s_h[0][tid];

    // new_j[b][i][jcol] = w_hh[i][jcol] + (M - w_hh[jcol][i])
    #pragma unroll
    for (int m = 0; m < 16; ++m) {
        const int i = rbase + 16 * m;
        dout[NJ_OFF + ((size_t)b * HH + i) * HH + jcol] =
            w_hh[(size_t)i * HH + jcol] + M[m] - s_wt[q][i];
    }
}

extern "C" void kernel_launch(void* const* d_in, const int* in_sizes, int n_in,
                              void* d_out, int out_size, void* d_ws, size_t ws_size,
                              hipStream_t stream) {
    (void)in_sizes; (void)n_in; (void)out_size; (void)ws_size;
    const float* x     = (const float*)d_in[0];
    const float* h0    = (const float*)d_in[1];
    const float* w_in  = (const float*)d_in[2];
    const float* w_hh  = (const float*)d_in[3];
    const float* b_hh  = (const float*)d_in[4];
    const float* w_out = (const float*)d_in[5];
    const float* nper  = (const float*)d_in[6];
    const float* sn    = (const float*)d_in[7];
    const int*   pt    = (const int*)d_in[8];
    float* dout        = (float*)d_out;
    u64* ws            = (u64*)d_ws;

    // zero the tagged slots each launch: tags in [1,64]; a replayed graph
    // must not see the previous launch's tags as valid.
    hipMemsetAsync(d_ws, 0, (size_t)BB * 2 * NSUB * 16 * sizeof(u64), stream);

    rnn_all<<<dim3(NBLK), dim3(256), 0, stream>>>(
        x, h0, w_in, w_hh, b_hh, w_out, nper, sn, pt, dout, ws);
}